// Round 13
// baseline (159.415 us; speedup 1.0000x reference)
//
#include <hip/hip_runtime.h>
#include <hip/hip_bf16.h>
#include <cstdint>

#define HH 4
#define CC 64
#define KDIM 256   // IN_CH
#define NOUT 256   // H*C
#define BM 64
#define BK 64
#define CAP 96     // max degree capacity (Poisson(16): P(deg>=96) ~ 1e-40)

typedef __attribute__((ext_vector_type(8))) short bf16x8;
typedef __attribute__((ext_vector_type(4))) float f32x4;
typedef unsigned short ushort_t;

__device__ __forceinline__ unsigned short f2bf(float f) {
  unsigned u = __float_as_uint(f);
  unsigned r = (u + 0x7fff + ((u >> 16) & 1)) >> 16;  // RNE
  return (unsigned short)r;
}
__device__ __forceinline__ unsigned pk2bf(float lo, float hi) {
  return (unsigned)f2bf(lo) | ((unsigned)f2bf(hi) << 16);
}

// ---------------- fused: convert W to bf16 (first wblocks) + bucket-CSR scatter ----------------
__global__ __launch_bounds__(256)
void scatter_convW(const float* __restrict__ W, ushort_t* __restrict__ Wb,
                   const int* __restrict__ ei, int* __restrict__ cnt,
                   int* __restrict__ bucket, int wblocks, int E) {
  if ((int)blockIdx.x < wblocks) {
    int i = ((int)blockIdx.x * 256 + threadIdx.x) * 8;   // < 65536
    float4 a = *(const float4*)(W + i);
    float4 b = *(const float4*)(W + i + 4);
    uint4 o;
    o.x = pk2bf(a.x, a.y); o.y = pk2bf(a.z, a.w);
    o.z = pk2bf(b.x, b.y); o.w = pk2bf(b.z, b.w);
    *(uint4*)(Wb + i) = o;
  } else {
    int t = ((int)blockIdx.x - wblocks) * 256 + threadIdx.x;
    if (t < E) {
      int s = ei[t];
      int d = ei[E + t];
      int pos = atomicAdd(&cnt[d], 1);
      if (pos < CAP)
        __builtin_nontemporal_store(s, &bucket[(size_t)d * CAP + pos]);
    }
  }
}

#define GLOAD_LDS16(g, l) \
  __builtin_amdgcn_global_load_lds((__attribute__((address_space(1))) const void*)(g), \
                                   (__attribute__((address_space(3))) void*)(l), 16, 0, 0)

// ---------------- MFMA GEMM 64x256, T4 pipelined: Wh(bf16) = x(fp32) @ Wb^T + fused scores ----------------
// One block = 64 rows x all 256 cols; wave w owns head w. x read exactly once.
// Per K-step: issue B global_load_lds (8/thr), issue NEXT A reg-loads (4/thr, after B),
// s_waitcnt vmcnt(4) => B drained (in-order retirement), A(k+1) flies across the barrier.
__global__ __launch_bounds__(256)
void gemm_direct(const float* __restrict__ X, const ushort_t* __restrict__ Wb,
                 ushort_t* __restrict__ Wh, float* __restrict__ s_src,
                 float* __restrict__ s_dst, const float* __restrict__ att, int M) {
  __shared__ char As[BM * BK * 2];       // 8 KB
  __shared__ char Bs[NOUT * BK * 2];     // 32 KB
  const int tid = threadIdx.x;
  const int lane = tid & 63;
  const int w = tid >> 6;
  const int row0 = blockIdx.x * BM;

  const int arow = tid >> 2;             // 0..63
  const int akoff = (tid & 3) * 16;
  const bool aval = (row0 + arow) < M;
  // clamped row so loads are ALWAYS issued (uniform per-wave vmcnt counts)
  const int arow_c = aval ? (row0 + arow) : (M - 1);
  const float* gx_base = X + (size_t)arow_c * KDIM + akoff;

  f32x4 acc[4][4] = {};
  float4 f[4];

#define LOADA(k0_)                                                  \
  {                                                                 \
    _Pragma("unroll")                                               \
    for (int i_ = 0; i_ < 4; ++i_)                                  \
      f[i_] = *(const float4*)(gx_base + (k0_) + i_ * 4);           \
  }

  LOADA(0);

#pragma unroll
  for (int k = 0; k < 4; ++k) {
    const int k0 = k * BK;
    // ---- cvt + swizzled LDS write of A(k) from regs ----
    {
      float4 g0 = aval ? f[0] : make_float4(0.f, 0.f, 0.f, 0.f);
      float4 g1 = aval ? f[1] : make_float4(0.f, 0.f, 0.f, 0.f);
      float4 g2 = aval ? f[2] : make_float4(0.f, 0.f, 0.f, 0.f);
      float4 g3 = aval ? f[3] : make_float4(0.f, 0.f, 0.f, 0.f);
      uint4 o0, o1;
      o0.x = pk2bf(g0.x, g0.y); o0.y = pk2bf(g0.z, g0.w);
      o0.z = pk2bf(g1.x, g1.y); o0.w = pk2bf(g1.z, g1.w);
      o1.x = pk2bf(g2.x, g2.y); o1.y = pk2bf(g2.z, g2.w);
      o1.z = pk2bf(g3.x, g3.y); o1.w = pk2bf(g3.z, g3.w);
      int q0 = (tid & 3) * 2;
      *(uint4*)(As + (arow * 8 + (q0 ^ (arow & 7))) * 16) = o0;
      *(uint4*)(As + (arow * 8 + ((q0 + 1) ^ (arow & 7))) * 16) = o1;
    }
    // ---- stage B(k): 8 global_load_lds ----
#pragma unroll
    for (int i = 0; i < 8; ++i) {
      int c = i * 256 + tid;
      int row = c >> 3, q = (c & 7) ^ (row & 7);
      const ushort_t* gptr = Wb + (size_t)row * KDIM + k0 + q * 8;
      GLOAD_LDS16(gptr, Bs + c * 16);
    }
    // ---- issue NEXT A loads (after B, so vmcnt(4) leaves exactly these in flight) ----
    if (k < 3) LOADA((k + 1) * BK);
    if (k < 3) {
      asm volatile("s_waitcnt vmcnt(4) lgkmcnt(0)" ::: "memory");
    } else {
      asm volatile("s_waitcnt vmcnt(0) lgkmcnt(0)" ::: "memory");
    }
    __builtin_amdgcn_sched_barrier(0);
    __builtin_amdgcn_s_barrier();
    asm volatile("" ::: "memory");

    // ---- compute(k) ----
#pragma unroll
    for (int kk = 0; kk < 2; ++kk) {
      bf16x8 aF[4], bF[4];
      int qq = kk * 4 + (lane >> 4);
#pragma unroll
      for (int rt = 0; rt < 4; ++rt) {
        int r = rt * 16 + (lane & 15);
        int phys = qq ^ (r & 7);
        aF[rt] = *(const bf16x8*)(As + r * 128 + phys * 16);
      }
#pragma unroll
      for (int ct = 0; ct < 4; ++ct) {
        int cl = w * 64 + ct * 16 + (lane & 15);
        int phys = qq ^ (cl & 7);
        bF[ct] = *(const bf16x8*)(Bs + cl * 128 + phys * 16);
      }
#pragma unroll
      for (int rt = 0; rt < 4; ++rt)
#pragma unroll
        for (int ct = 0; ct < 4; ++ct)
          acc[rt][ct] = __builtin_amdgcn_mfma_f32_16x16x32_bf16(aF[rt], bF[ct], acc[rt][ct], 0, 0, 0);
    }
    if (k < 3) {
      asm volatile("" ::: "memory");
      __builtin_amdgcn_s_barrier();
      __builtin_amdgcn_sched_barrier(0);
    }
  }

  const int h = w;
  float att_s[4], att_d[4];
#pragma unroll
  for (int ct = 0; ct < 4; ++ct) {
    att_s[ct] = att[h * 2 * CC + ct * 16 + (lane & 15)];
    att_d[ct] = att[h * 2 * CC + CC + ct * 16 + (lane & 15)];
  }
#pragma unroll
  for (int rt = 0; rt < 4; ++rt) {
#pragma unroll
    for (int reg = 0; reg < 4; ++reg) {
      float ls = 0.f, ld_ = 0.f;
#pragma unroll
      for (int ct = 0; ct < 4; ++ct) {
        float a = acc[rt][ct][reg];
        ls += a * att_s[ct];
        ld_ += a * att_d[ct];
      }
#pragma unroll
      for (int off = 1; off < 16; off <<= 1) {
        ls += __shfl_xor(ls, off);
        ld_ += __shfl_xor(ld_, off);
      }
      int r = row0 + rt * 16 + (lane >> 4) * 4 + reg;
      if ((lane & 15) == 0 && r < M) {
        s_src[r * HH + h] = ls;
        s_dst[r * HH + h] = ld_;
      }
    }
  }

#pragma unroll
  for (int rt = 0; rt < 4; ++rt) {
#pragma unroll
    for (int reg = 0; reg < 4; ++reg) {
      int r = row0 + rt * 16 + (lane >> 4) * 4 + reg;
      if (r < M) {
#pragma unroll
        for (int ct = 0; ct < 4; ++ct) {
          int ccol = w * 64 + ct * 16 + (lane & 15);
          Wh[(size_t)r * NOUT + ccol] = f2bf(acc[rt][ct][reg]);
        }
      }
    }
  }
}

// ---------------- aggregation: bucket CSR, inline p=exp(leaky(.)), 4-deep MLP, fused ELU ----------------
__global__ __launch_bounds__(256)
void aggregate(const ushort_t* __restrict__ Wh, const float* __restrict__ s_src,
               const float* __restrict__ s_dst, const int* __restrict__ cnt,
               const int* __restrict__ bucket, float* __restrict__ out, int N) {
  int wid = (int)((blockIdx.x * 256 + threadIdx.x) >> 6);
  int lane = threadIdx.x & 63;
  if (wid >= N) return;
  int half = lane >> 5, cl = lane & 31;
  int h = cl >> 3;
  int deg = cnt[wid];
  if (deg > CAP) deg = CAP;
  int start = wid * CAP;
  int end = start + deg;
  float sd = s_dst[wid * HH + h];
  float acc[8] = {};
  float dsum = 0.f;
  int idx = start + half;
  for (; idx + 6 < end; idx += 8) {
    int s[4];
#pragma unroll
    for (int k = 0; k < 4; ++k) s[k] = bucket[idx + 2 * k];
    float p[4];
    uint4 wv[4];
#pragma unroll
    for (int k = 0; k < 4; ++k) {
      float v = s_src[s[k] * HH + h] + sd;
      v = v > 0.f ? v : 0.2f * v;
      p[k] = __expf(v);
      wv[k] = *(const uint4*)(Wh + (size_t)s[k] * NOUT + cl * 8);
    }
#pragma unroll
    for (int k = 0; k < 4; ++k) {
      dsum += p[k];
#pragma unroll
      for (int j = 0; j < 4; ++j) {
        unsigned u = ((const unsigned*)&wv[k])[j];
        acc[2 * j]     += p[k] * __uint_as_float(u << 16);
        acc[2 * j + 1] += p[k] * __uint_as_float(u & 0xffff0000u);
      }
    }
  }
  for (; idx < end; idx += 2) {
    int s0 = bucket[idx];
    float v = s_src[s0 * HH + h] + sd;
    v = v > 0.f ? v : 0.2f * v;
    float p0 = __expf(v);
    uint4 w0 = *(const uint4*)(Wh + (size_t)s0 * NOUT + cl * 8);
    dsum += p0;
#pragma unroll
    for (int j = 0; j < 4; ++j) {
      unsigned u0 = ((const unsigned*)&w0)[j];
      acc[2 * j]     += p0 * __uint_as_float(u0 << 16);
      acc[2 * j + 1] += p0 * __uint_as_float(u0 & 0xffff0000u);
    }
  }
#pragma unroll
  for (int j = 0; j < 8; ++j) acc[j] += __shfl_xor(acc[j], 32);
  dsum += __shfl_xor(dsum, 32);
  if (half == 0) {
    float rd = 1.0f / (dsum + 1e-16f);
    float o[8];
#pragma unroll
    for (int j = 0; j < 8; ++j) {
      float a = acc[j] * rd;
      o[j] = a > 0.f ? a : expm1f(a);
    }
    float* op = out + (size_t)wid * NOUT + cl * 8;
    *(float4*)op = make_float4(o[0], o[1], o[2], o[3]);
    *(float4*)(op + 4) = make_float4(o[4], o[5], o[6], o[7]);
  }
}

extern "C" void kernel_launch(void* const* d_in, const int* in_sizes, int n_in,
                              void* d_out, int out_size, void* d_ws, size_t ws_size,
                              hipStream_t stream) {
  const float* x = (const float*)d_in[0];
  const int* ei = (const int*)d_in[1];
  const float* W = (const float*)d_in[2];
  const float* att = (const float*)d_in[3];
  float* out = (float*)d_out;
  const int N = in_sizes[0] / KDIM;
  const int E = in_sizes[1] / 2;
  const int NPAD = ((N + BM - 1) / BM) * BM;

  char* p = (char*)d_ws;
  auto alloc = [&](size_t bytes) {
    char* r = p;
    p += (bytes + 255) & ~(size_t)255;
    return r;
  };
  ushort_t* Wb   = (ushort_t*)alloc((size_t)NOUT * KDIM * 2);
  ushort_t* Wh   = (ushort_t*)alloc((size_t)NPAD * NOUT * 2);
  float* s_src   = (float*)alloc((size_t)N * HH * 4);
  float* s_dst   = (float*)alloc((size_t)N * HH * 4);
  int* cnt       = (int*)alloc((size_t)N * 4);
  int* bucket    = (int*)alloc((size_t)N * CAP * 4);

  (void)hipMemsetAsync(cnt, 0, (size_t)N * 4, stream);

  const int wblocks = (NOUT * KDIM) / (256 * 8);  // 32
  int eblocks = (E + 255) / 256;
  scatter_convW<<<wblocks + eblocks, 256, 0, stream>>>(W, Wb, ei, cnt, bucket, wblocks, E);

  gemm_direct<<<NPAD / BM, 256, 0, stream>>>(x, Wb, Wh, s_src, s_dst, att, N);

  aggregate<<<(N + 3) / 4, 256, 0, stream>>>(Wh, s_src, s_dst, cnt, bucket, out, N);
}

// Round 14
// 154.140 us; speedup vs baseline: 1.0342x; 1.0342x over previous
//
#include <hip/hip_runtime.h>
#include <hip/hip_bf16.h>
#include <cstdint>

#define HH 4
#define CC 64
#define KDIM 256   // IN_CH
#define NOUT 256   // H*C
#define BM 64
#define BK 64
#define CAP 96     // max degree capacity (Poisson(16): P(deg>=96) ~ 1e-40)

typedef __attribute__((ext_vector_type(8))) short bf16x8;
typedef __attribute__((ext_vector_type(4))) float f32x4;
typedef unsigned short ushort_t;

__device__ __forceinline__ unsigned short f2bf(float f) {
  unsigned u = __float_as_uint(f);
  unsigned r = (u + 0x7fff + ((u >> 16) & 1)) >> 16;  // RNE
  return (unsigned short)r;
}
__device__ __forceinline__ unsigned pk2bf(float lo, float hi) {
  return (unsigned)f2bf(lo) | ((unsigned)f2bf(hi) << 16);
}

// ---------------- fused: convert W to bf16 (first wblocks) + bucket-CSR scatter ----------------
__global__ __launch_bounds__(256)
void scatter_convW(const float* __restrict__ W, ushort_t* __restrict__ Wb,
                   const int* __restrict__ ei, int* __restrict__ cnt,
                   int* __restrict__ bucket, int wblocks, int E) {
  if ((int)blockIdx.x < wblocks) {
    int i = ((int)blockIdx.x * 256 + threadIdx.x) * 8;   // < 65536
    float4 a = *(const float4*)(W + i);
    float4 b = *(const float4*)(W + i + 4);
    uint4 o;
    o.x = pk2bf(a.x, a.y); o.y = pk2bf(a.z, a.w);
    o.z = pk2bf(b.x, b.y); o.w = pk2bf(b.z, b.w);
    *(uint4*)(Wb + i) = o;
  } else {
    int t = ((int)blockIdx.x - wblocks) * 256 + threadIdx.x;
    if (t < E) {
      int s = ei[t];
      int d = ei[E + t];
      int pos = atomicAdd(&cnt[d], 1);
      if (pos < CAP) bucket[(size_t)d * CAP + pos] = s;
    }
  }
}

#define GLOAD_LDS16(g, l) \
  __builtin_amdgcn_global_load_lds((__attribute__((address_space(1))) const void*)(g), \
                                   (__attribute__((address_space(3))) void*)(l), 16, 0, 0)

// ---------------- MFMA GEMM 64x256: Wh(bf16) = x(fp32) @ Wb^T + fused scores ----------------
// One block = 64 rows x all 256 cols; wave w owns head w. x read exactly once.
__global__ __launch_bounds__(256)
void gemm_direct(const float* __restrict__ X, const ushort_t* __restrict__ Wb,
                 ushort_t* __restrict__ Wh, float* __restrict__ s_src,
                 float* __restrict__ s_dst, const float* __restrict__ att, int M) {
  __shared__ char As[BM * BK * 2];       // 8 KB
  __shared__ char Bs[NOUT * BK * 2];     // 32 KB
  const int tid = threadIdx.x;
  const int lane = tid & 63;
  const int w = tid >> 6;
  const int row0 = blockIdx.x * BM;

  const int arow = tid >> 2;             // 0..63
  const int akoff = (tid & 3) * 16;
  const bool aval = (row0 + arow) < M;

  f32x4 acc[4][4] = {};

  for (int k0 = 0; k0 < KDIM; k0 += BK) {
    {
      const float* gx = X + (size_t)(row0 + arow) * KDIM + k0 + akoff;
      float4 f[4];
#pragma unroll
      for (int i = 0; i < 4; ++i)
        f[i] = aval ? *(const float4*)(gx + i * 4) : make_float4(0.f, 0.f, 0.f, 0.f);
#pragma unroll
      for (int hfl = 0; hfl < 2; ++hfl) {
        uint4 o;
        o.x = pk2bf(f[2 * hfl].x, f[2 * hfl].y);
        o.y = pk2bf(f[2 * hfl].z, f[2 * hfl].w);
        o.z = pk2bf(f[2 * hfl + 1].x, f[2 * hfl + 1].y);
        o.w = pk2bf(f[2 * hfl + 1].z, f[2 * hfl + 1].w);
        int q = (tid & 3) * 2 + hfl;
        int phys = q ^ (arow & 7);
        *(uint4*)(As + (arow * 8 + phys) * 16) = o;
      }
    }
#pragma unroll
    for (int i = 0; i < 8; ++i) {
      int c = i * 256 + tid;
      int row = c >> 3, q = (c & 7) ^ (row & 7);
      const ushort_t* gptr = Wb + (size_t)row * KDIM + k0 + q * 8;
      GLOAD_LDS16(gptr, Bs + c * 16);
    }
    __syncthreads();

#pragma unroll
    for (int kk = 0; kk < 2; ++kk) {
      bf16x8 aF[4], bF[4];
      int qq = kk * 4 + (lane >> 4);
#pragma unroll
      for (int rt = 0; rt < 4; ++rt) {
        int r = rt * 16 + (lane & 15);
        int phys = qq ^ (r & 7);
        aF[rt] = *(const bf16x8*)(As + r * 128 + phys * 16);
      }
#pragma unroll
      for (int ct = 0; ct < 4; ++ct) {
        int cl = w * 64 + ct * 16 + (lane & 15);
        int phys = qq ^ (cl & 7);
        bF[ct] = *(const bf16x8*)(Bs + cl * 128 + phys * 16);
      }
#pragma unroll
      for (int rt = 0; rt < 4; ++rt)
#pragma unroll
        for (int ct = 0; ct < 4; ++ct)
          acc[rt][ct] = __builtin_amdgcn_mfma_f32_16x16x32_bf16(aF[rt], bF[ct], acc[rt][ct], 0, 0, 0);
    }
    __syncthreads();
  }

  const int h = w;
  float att_s[4], att_d[4];
#pragma unroll
  for (int ct = 0; ct < 4; ++ct) {
    att_s[ct] = att[h * 2 * CC + ct * 16 + (lane & 15)];
    att_d[ct] = att[h * 2 * CC + CC + ct * 16 + (lane & 15)];
  }
#pragma unroll
  for (int rt = 0; rt < 4; ++rt) {
#pragma unroll
    for (int reg = 0; reg < 4; ++reg) {
      float ls = 0.f, ld_ = 0.f;
#pragma unroll
      for (int ct = 0; ct < 4; ++ct) {
        float a = acc[rt][ct][reg];
        ls += a * att_s[ct];
        ld_ += a * att_d[ct];
      }
#pragma unroll
      for (int off = 1; off < 16; off <<= 1) {
        ls += __shfl_xor(ls, off);
        ld_ += __shfl_xor(ld_, off);
      }
      int r = row0 + rt * 16 + (lane >> 4) * 4 + reg;
      if ((lane & 15) == 0 && r < M) {
        s_src[r * HH + h] = ls;
        s_dst[r * HH + h] = ld_;
      }
    }
  }

#pragma unroll
  for (int rt = 0; rt < 4; ++rt) {
#pragma unroll
    for (int reg = 0; reg < 4; ++reg) {
      int r = row0 + rt * 16 + (lane >> 4) * 4 + reg;
      if (r < M) {
#pragma unroll
        for (int ct = 0; ct < 4; ++ct) {
          int ccol = w * 64 + ct * 16 + (lane & 15);
          Wh[(size_t)r * NOUT + ccol] = f2bf(acc[rt][ct][reg]);
        }
      }
    }
  }
}

// ---------------- aggregation: bucket CSR, inline p, 6-deep MLP per half, fused ELU ----------------
__global__ __launch_bounds__(256)
void aggregate(const ushort_t* __restrict__ Wh, const float* __restrict__ s_src,
               const float* __restrict__ s_dst, const int* __restrict__ cnt,
               const int* __restrict__ bucket, float* __restrict__ out, int N) {
  int wid = (int)((blockIdx.x * 256 + threadIdx.x) >> 6);
  int lane = threadIdx.x & 63;
  if (wid >= N) return;
  int half = lane >> 5, cl = lane & 31;
  int h = cl >> 3;
  int deg = cnt[wid];
  if (deg > CAP) deg = CAP;
  int start = wid * CAP;
  int end = start + deg;
  float sd = s_dst[wid * HH + h];
  float acc[8] = {};
  float dsum = 0.f;
  int idx = start + half;
  // 6 edges in flight per half (12 per wave)
  for (; idx + 10 < end; idx += 12) {
    int s[6];
#pragma unroll
    for (int k = 0; k < 6; ++k) s[k] = bucket[idx + 2 * k];
    float p[6];
    uint4 wv[6];
#pragma unroll
    for (int k = 0; k < 6; ++k) {
      float v = s_src[s[k] * HH + h] + sd;
      v = v > 0.f ? v : 0.2f * v;
      p[k] = __expf(v);
      wv[k] = *(const uint4*)(Wh + (size_t)s[k] * NOUT + cl * 8);
    }
#pragma unroll
    for (int k = 0; k < 6; ++k) {
      dsum += p[k];
#pragma unroll
      for (int j = 0; j < 4; ++j) {
        unsigned u = ((const unsigned*)&wv[k])[j];
        acc[2 * j]     += p[k] * __uint_as_float(u << 16);
        acc[2 * j + 1] += p[k] * __uint_as_float(u & 0xffff0000u);
      }
    }
  }
  for (; idx < end; idx += 2) {
    int s0 = bucket[idx];
    float v = s_src[s0 * HH + h] + sd;
    v = v > 0.f ? v : 0.2f * v;
    float p0 = __expf(v);
    uint4 w0 = *(const uint4*)(Wh + (size_t)s0 * NOUT + cl * 8);
    dsum += p0;
#pragma unroll
    for (int j = 0; j < 4; ++j) {
      unsigned u0 = ((const unsigned*)&w0)[j];
      acc[2 * j]     += p0 * __uint_as_float(u0 << 16);
      acc[2 * j + 1] += p0 * __uint_as_float(u0 & 0xffff0000u);
    }
  }
#pragma unroll
  for (int j = 0; j < 8; ++j) acc[j] += __shfl_xor(acc[j], 32);
  dsum += __shfl_xor(dsum, 32);
  if (half == 0) {
    float rd = 1.0f / (dsum + 1e-16f);
    float o[8];
#pragma unroll
    for (int j = 0; j < 8; ++j) {
      float a = acc[j] * rd;
      o[j] = a > 0.f ? a : expm1f(a);
    }
    float* op = out + (size_t)wid * NOUT + cl * 8;
    *(float4*)op = make_float4(o[0], o[1], o[2], o[3]);
    *(float4*)(op + 4) = make_float4(o[4], o[5], o[6], o[7]);
  }
}

extern "C" void kernel_launch(void* const* d_in, const int* in_sizes, int n_in,
                              void* d_out, int out_size, void* d_ws, size_t ws_size,
                              hipStream_t stream) {
  const float* x = (const float*)d_in[0];
  const int* ei = (const int*)d_in[1];
  const float* W = (const float*)d_in[2];
  const float* att = (const float*)d_in[3];
  float* out = (float*)d_out;
  const int N = in_sizes[0] / KDIM;
  const int E = in_sizes[1] / 2;
  const int NPAD = ((N + BM - 1) / BM) * BM;

  char* p = (char*)d_ws;
  auto alloc = [&](size_t bytes) {
    char* r = p;
    p += (bytes + 255) & ~(size_t)255;
    return r;
  };
  ushort_t* Wb   = (ushort_t*)alloc((size_t)NOUT * KDIM * 2);
  ushort_t* Wh   = (ushort_t*)alloc((size_t)NPAD * NOUT * 2);
  float* s_src   = (float*)alloc((size_t)N * HH * 4);
  float* s_dst   = (float*)alloc((size_t)N * HH * 4);
  int* cnt       = (int*)alloc((size_t)N * 4);
  int* bucket    = (int*)alloc((size_t)N * CAP * 4);

  (void)hipMemsetAsync(cnt, 0, (size_t)N * 4, stream);

  const int wblocks = (NOUT * KDIM) / (256 * 8);  // 32
  int eblocks = (E + 255) / 256;
  scatter_convW<<<wblocks + eblocks, 256, 0, stream>>>(W, Wb, ei, cnt, bucket, wblocks, E);

  gemm_direct<<<NPAD / BM, 256, 0, stream>>>(x, Wb, Wh, s_src, s_dst, att, N);

  aggregate<<<(N + 3) / 4, 256, 0, stream>>>(Wh, s_src, s_dst, cnt, bucket, out, N);
}

// Round 15
// 151.631 us; speedup vs baseline: 1.0513x; 1.0166x over previous
//
#include <hip/hip_runtime.h>
#include <hip/hip_bf16.h>
#include <cstdint>

#define HH 4
#define CC 64
#define KDIM 256   // IN_CH
#define NOUT 256   // H*C
#define BM 64
#define BK 64
#define CAP 96     // max degree capacity (Poisson(16): P(deg>=96) ~ 1e-40)

typedef __attribute__((ext_vector_type(8))) short bf16x8;
typedef __attribute__((ext_vector_type(4))) float f32x4;
typedef unsigned short ushort_t;

__device__ __forceinline__ unsigned short f2bf(float f) {
  unsigned u = __float_as_uint(f);
  unsigned r = (u + 0x7fff + ((u >> 16) & 1)) >> 16;  // RNE
  return (unsigned short)r;
}
__device__ __forceinline__ unsigned pk2bf(float lo, float hi) {
  return (unsigned)f2bf(lo) | ((unsigned)f2bf(hi) << 16);
}

// ---------------- pure bucket-CSR scatter ----------------
__global__ __launch_bounds__(256)
void scatter_k(const int* __restrict__ ei, int* __restrict__ cnt,
               int* __restrict__ bucket, int E) {
  int t = (int)blockIdx.x * 256 + threadIdx.x;
  if (t < E) {
    int s = ei[t];
    int d = ei[E + t];
    int pos = atomicAdd(&cnt[d], 1);
    if (pos < CAP) bucket[(size_t)d * CAP + pos] = s;
  }
}

// ---------------- MFMA GEMM 64x256: Wh(bf16) = x(fp32) @ W(fp32)^T + fused scores ----------------
// One block = 64 rows x all 256 cols; wave w owns head w. x read exactly once.
// Both A and B reg-staged fp32 -> bf16 -> swizzled LDS (W is L2-resident, 256 KB).
// Preamble: each block zeroes 64 entries of cnt (deletes the memset dispatch).
__global__ __launch_bounds__(256)
void gemm_direct(const float* __restrict__ X, const float* __restrict__ W,
                 ushort_t* __restrict__ Wh, float* __restrict__ s_src,
                 float* __restrict__ s_dst, const float* __restrict__ att,
                 int M, int* __restrict__ cnt, int N) {
  __shared__ char As[BM * BK * 2];       // 8 KB
  __shared__ char Bs[NOUT * BK * 2];     // 32 KB
  const int tid = threadIdx.x;
  const int lane = tid & 63;
  const int w = tid >> 6;
  const int row0 = blockIdx.x * BM;

  // zero cnt slice (next dispatch depends on it)
  if (tid < 64) {
    int i = (int)blockIdx.x * 64 + tid;
    if (i < N) cnt[i] = 0;
  }

  const int arow = tid >> 2;             // 0..63
  const int akoff = (tid & 3) * 16;
  const bool aval = (row0 + arow) < M;

  f32x4 acc[4][4] = {};

  for (int k0 = 0; k0 < KDIM; k0 += BK) {
    // ---- stage A: 64x64 fp32 -> bf16 LDS ----
    {
      const float* gx = X + (size_t)(row0 + arow) * KDIM + k0 + akoff;
      float4 f[4];
#pragma unroll
      for (int i = 0; i < 4; ++i)
        f[i] = aval ? *(const float4*)(gx + i * 4) : make_float4(0.f, 0.f, 0.f, 0.f);
#pragma unroll
      for (int hfl = 0; hfl < 2; ++hfl) {
        uint4 o;
        o.x = pk2bf(f[2 * hfl].x, f[2 * hfl].y);
        o.y = pk2bf(f[2 * hfl].z, f[2 * hfl].w);
        o.z = pk2bf(f[2 * hfl + 1].x, f[2 * hfl + 1].y);
        o.w = pk2bf(f[2 * hfl + 1].z, f[2 * hfl + 1].w);
        int q = (tid & 3) * 2 + hfl;
        int phys = q ^ (arow & 7);
        *(uint4*)(As + (arow * 8 + phys) * 16) = o;
      }
    }
    // ---- stage B: 256x64 fp32 W -> bf16 LDS (L2-resident source) ----
#pragma unroll
    for (int i = 0; i < 8; ++i) {
      int c = i * 256 + tid;
      int row = c >> 3, q = c & 7;
      const float* gw = W + (size_t)row * KDIM + k0 + q * 8;
      float4 g0 = *(const float4*)gw;
      float4 g1 = *(const float4*)(gw + 4);
      uint4 o;
      o.x = pk2bf(g0.x, g0.y); o.y = pk2bf(g0.z, g0.w);
      o.z = pk2bf(g1.x, g1.y); o.w = pk2bf(g1.z, g1.w);
      int phys = q ^ (row & 7);
      *(uint4*)(Bs + (row * 8 + phys) * 16) = o;
    }
    __syncthreads();

#pragma unroll
    for (int kk = 0; kk < 2; ++kk) {
      bf16x8 aF[4], bF[4];
      int qq = kk * 4 + (lane >> 4);
#pragma unroll
      for (int rt = 0; rt < 4; ++rt) {
        int r = rt * 16 + (lane & 15);
        int phys = qq ^ (r & 7);
        aF[rt] = *(const bf16x8*)(As + r * 128 + phys * 16);
      }
#pragma unroll
      for (int ct = 0; ct < 4; ++ct) {
        int cl = w * 64 + ct * 16 + (lane & 15);
        int phys = qq ^ (cl & 7);
        bF[ct] = *(const bf16x8*)(Bs + cl * 128 + phys * 16);
      }
#pragma unroll
      for (int rt = 0; rt < 4; ++rt)
#pragma unroll
        for (int ct = 0; ct < 4; ++ct)
          acc[rt][ct] = __builtin_amdgcn_mfma_f32_16x16x32_bf16(aF[rt], bF[ct], acc[rt][ct], 0, 0, 0);
    }
    __syncthreads();
  }

  const int h = w;
  float att_s[4], att_d[4];
#pragma unroll
  for (int ct = 0; ct < 4; ++ct) {
    att_s[ct] = att[h * 2 * CC + ct * 16 + (lane & 15)];
    att_d[ct] = att[h * 2 * CC + CC + ct * 16 + (lane & 15)];
  }
#pragma unroll
  for (int rt = 0; rt < 4; ++rt) {
#pragma unroll
    for (int reg = 0; reg < 4; ++reg) {
      float ls = 0.f, ld_ = 0.f;
#pragma unroll
      for (int ct = 0; ct < 4; ++ct) {
        float a = acc[rt][ct][reg];
        ls += a * att_s[ct];
        ld_ += a * att_d[ct];
      }
#pragma unroll
      for (int off = 1; off < 16; off <<= 1) {
        ls += __shfl_xor(ls, off);
        ld_ += __shfl_xor(ld_, off);
      }
      int r = row0 + rt * 16 + (lane >> 4) * 4 + reg;
      if ((lane & 15) == 0 && r < M) {
        s_src[r * HH + h] = ls;
        s_dst[r * HH + h] = ld_;
      }
    }
  }

#pragma unroll
  for (int rt = 0; rt < 4; ++rt) {
#pragma unroll
    for (int reg = 0; reg < 4; ++reg) {
      int r = row0 + rt * 16 + (lane >> 4) * 4 + reg;
      if (r < M) {
#pragma unroll
        for (int ct = 0; ct < 4; ++ct) {
          int ccol = w * 64 + ct * 16 + (lane & 15);
          Wh[(size_t)r * NOUT + ccol] = f2bf(acc[rt][ct][reg]);
        }
      }
    }
  }
}

// ---------------- aggregation: bucket CSR, inline p=exp(leaky(.)), 4-deep MLP, fused ELU ----------------
__global__ __launch_bounds__(256)
void aggregate(const ushort_t* __restrict__ Wh, const float* __restrict__ s_src,
               const float* __restrict__ s_dst, const int* __restrict__ cnt,
               const int* __restrict__ bucket, float* __restrict__ out, int N) {
  int wid = (int)((blockIdx.x * 256 + threadIdx.x) >> 6);
  int lane = threadIdx.x & 63;
  if (wid >= N) return;
  int half = lane >> 5, cl = lane & 31;
  int h = cl >> 3;
  int deg = cnt[wid];
  if (deg > CAP) deg = CAP;
  int start = wid * CAP;
  int end = start + deg;
  float sd = s_dst[wid * HH + h];
  float acc[8] = {};
  float dsum = 0.f;
  int idx = start + half;
  for (; idx + 6 < end; idx += 8) {
    int s[4];
#pragma unroll
    for (int k = 0; k < 4; ++k) s[k] = bucket[idx + 2 * k];
    float p[4];
    uint4 wv[4];
#pragma unroll
    for (int k = 0; k < 4; ++k) {
      float v = s_src[s[k] * HH + h] + sd;
      v = v > 0.f ? v : 0.2f * v;
      p[k] = __expf(v);
      wv[k] = *(const uint4*)(Wh + (size_t)s[k] * NOUT + cl * 8);
    }
#pragma unroll
    for (int k = 0; k < 4; ++k) {
      dsum += p[k];
#pragma unroll
      for (int j = 0; j < 4; ++j) {
        unsigned u = ((const unsigned*)&wv[k])[j];
        acc[2 * j]     += p[k] * __uint_as_float(u << 16);
        acc[2 * j + 1] += p[k] * __uint_as_float(u & 0xffff0000u);
      }
    }
  }
  for (; idx < end; idx += 2) {
    int s0 = bucket[idx];
    float v = s_src[s0 * HH + h] + sd;
    v = v > 0.f ? v : 0.2f * v;
    float p0 = __expf(v);
    uint4 w0 = *(const uint4*)(Wh + (size_t)s0 * NOUT + cl * 8);
    dsum += p0;
#pragma unroll
    for (int j = 0; j < 4; ++j) {
      unsigned u0 = ((const unsigned*)&w0)[j];
      acc[2 * j]     += p0 * __uint_as_float(u0 << 16);
      acc[2 * j + 1] += p0 * __uint_as_float(u0 & 0xffff0000u);
    }
  }
#pragma unroll
  for (int j = 0; j < 8; ++j) acc[j] += __shfl_xor(acc[j], 32);
  dsum += __shfl_xor(dsum, 32);
  if (half == 0) {
    float rd = 1.0f / (dsum + 1e-16f);
    float o[8];
#pragma unroll
    for (int j = 0; j < 8; ++j) {
      float a = acc[j] * rd;
      o[j] = a > 0.f ? a : expm1f(a);
    }
    float* op = out + (size_t)wid * NOUT + cl * 8;
    *(float4*)op = make_float4(o[0], o[1], o[2], o[3]);
    *(float4*)(op + 4) = make_float4(o[4], o[5], o[6], o[7]);
  }
}

extern "C" void kernel_launch(void* const* d_in, const int* in_sizes, int n_in,
                              void* d_out, int out_size, void* d_ws, size_t ws_size,
                              hipStream_t stream) {
  const float* x = (const float*)d_in[0];
  const int* ei = (const int*)d_in[1];
  const float* W = (const float*)d_in[2];
  const float* att = (const float*)d_in[3];
  float* out = (float*)d_out;
  const int N = in_sizes[0] / KDIM;
  const int E = in_sizes[1] / 2;
  const int NPAD = ((N + BM - 1) / BM) * BM;

  char* p = (char*)d_ws;
  auto alloc = [&](size_t bytes) {
    char* r = p;
    p += (bytes + 255) & ~(size_t)255;
    return r;
  };
  ushort_t* Wh   = (ushort_t*)alloc((size_t)NPAD * NOUT * 2);
  float* s_src   = (float*)alloc((size_t)N * HH * 4);
  float* s_dst   = (float*)alloc((size_t)N * HH * 4);
  int* cnt       = (int*)alloc((size_t)N * 4);
  int* bucket    = (int*)alloc((size_t)N * CAP * 4);

  gemm_direct<<<NPAD / BM, 256, 0, stream>>>(x, W, Wh, s_src, s_dst, att, N, cnt, N);

  scatter_k<<<(E + 255) / 256, 256, 0, stream>>>(ei, cnt, bucket, E);

  aggregate<<<(N + 3) / 4, 256, 0, stream>>>(Wh, s_src, s_dst, cnt, bucket, out, N);
}